// Round 16
// baseline (438.211 us; speedup 1.0000x reference)
//
#include <hip/hip_runtime.h>
#include <math.h>

using short8  = __attribute__((ext_vector_type(8))) short;
using ushort8 = __attribute__((ext_vector_type(8))) unsigned short;
using f32x4   = __attribute__((ext_vector_type(4))) float;

constexpr int DIM = 1024, NB = 8, NH = 2, HD = 32;
constexpr float SCALE = 0.17677669529663687f;  // HD^-0.5, folded into wq at prep
constexpr int SXW = 1032;   // x-tile row stride (ushorts)
constexpr int SQW = 1544;   // qkv row stride (ushorts)
constexpr int NITER = 4;    // token tiles per WG (grid-stride pipeline)

__device__ __forceinline__ unsigned short f2bf(float f) {
  unsigned u = __float_as_uint(f);
  u += 0x7fff + ((u >> 16) & 1);  // RNE
  return (unsigned short)(u >> 16);
}
__device__ __forceinline__ float bf2f(unsigned short h) {
  return __uint_as_float((unsigned)h << 16);
}
__device__ __forceinline__ unsigned pack2bf(float lo, float hi) {
  return (unsigned)f2bf(lo) | ((unsigned)f2bf(hi) << 16);
}

// ---- prep: weights -> bf16 in MFMA fragment order (verified round 5/7) ----
__global__ __launch_bounds__(256) void prep_weights(
    const float* __restrict__ wq, const float* __restrict__ wk,
    const float* __restrict__ wv, const float* __restrict__ wf,
    unsigned short* __restrict__ ws)
{
  int gid = blockIdx.x * 256 + threadIdx.x;   // 0..262143
  if (gid < 196608) {
    int t = gid >> 11, r = gid & 2047;
    int s = r >> 9, l = (r >> 3) & 63, z = r & 7;
    int met = t >> 3, n = t & 7, m = met >> 2, et = met & 3;
    int fr = l & 15, fg = l >> 4;
    int e = et * 16 + fr, k = s * 32 + fg * 8 + z;
    const float* w = (m == 0) ? wq : (m == 1) ? wk : wv;
    float v = w[n * 8192 + k * 64 + e];
    if (m == 0) v *= SCALE;
    ws[gid] = f2bf(v);
  } else {
    int g2 = gid - 196608;
    int t = g2 >> 10, r = g2 & 1023;
    int s = r >> 9, l = (r >> 3) & 63, z = r & 7;
    int n = t >> 3, et = t & 7;
    int fr = l & 15, fg = l >> 4;
    int eo = et * 16 + fr, k = s * 32 + fg * 8 + z;
    ws[gid] = f2bf(wf[n * 8192 + k * 128 + eo]);
  }
}

// ---- fused kernel: R9 body verbatim, wrapped in a 4-tile pipeline ----
__global__ __launch_bounds__(512, 6) void gc_fused(
    const float* __restrict__ x,
    const unsigned short* __restrict__ wsw,   // 96 qkv tiles [2048 ush]
    const unsigned short* __restrict__ wsf,   // 64 wf tiles  [1024 ush]
    float* __restrict__ out)
{
  // overlays: stage-x rows at r*SXW; after barrier qkv rows at t*SQW.
  // per token row: q/attn_out [0,512) as n*64+h*32+dd | k [512,1024) same |
  // vT [1024,1536): 1024 + dd*16 + (h*8+n).   (R9 layout, proven 85.4 µs)
  __shared__ __align__(16) unsigned short smem[16 * SQW];   // 49408 B

  const int tid  = threadIdx.x;
  const int lane = tid & 63;
  const int w    = tid >> 6;
  const int fr   = lane & 15;
  const int fg   = lane >> 4;
  const long tile0 = (long)blockIdx.x * NITER;

  float4 xa[4], xc[4];                       // x prefetch registers (32 VGPR)
  {
    const float* xb = x + tile0 * 16 * DIM;
    #pragma unroll
    for (int jj = 0; jj < 4; ++jj) {
      int chunk = tid + 512 * jj;
      const float* src = xb + (long)(chunk >> 7) * DIM + (chunk & 127) * 8;
      xa[jj] = *reinterpret_cast<const float4*>(src);
      xc[jj] = *reinterpret_cast<const float4*>(src + 4);
    }
  }

  #pragma unroll 1
  for (int it = 0; it < NITER; ++it) {
    const long tok0 = (tile0 + it) * 16;

    // ---- convert prefetched x -> bf16 LDS (R9 staging, loads already done) ----
    {
      #pragma unroll
      for (int jj = 0; jj < 4; ++jj) {
        int chunk = tid + 512 * jj;
        ushort8 v;
        v[0] = f2bf(xa[jj].x); v[1] = f2bf(xa[jj].y);
        v[2] = f2bf(xa[jj].z); v[3] = f2bf(xa[jj].w);
        v[4] = f2bf(xc[jj].x); v[5] = f2bf(xc[jj].y);
        v[6] = f2bf(xc[jj].z); v[7] = f2bf(xc[jj].w);
        *reinterpret_cast<ushort8*>(&smem[(chunk >> 7) * SXW + (chunk & 127) * 8]) = v;
      }
    }
    __syncthreads();

    // ---- phase A: 96 QKV tiles over 8 waves, dbuf weight prefetch (R9) ----
    ushort4 qreg[12];
    {
      short8 wfr[2][4];
      const unsigned short* wp0 = wsw + (w * 12) * 2048 + lane * 8;
      #pragma unroll
      for (int s = 0; s < 4; ++s)
        wfr[0][s] = *reinterpret_cast<const short8*>(wp0 + s * 512);
      #pragma unroll
      for (int j = 0; j < 12; ++j) {
        const int cc = w * 12 + j;
        const int n  = cc & 7;
        if (j < 11) {
          const unsigned short* wpn = wsw + (cc + 1) * 2048 + lane * 8;
          #pragma unroll
          for (int s = 0; s < 4; ++s)
            wfr[(j + 1) & 1][s] = *reinterpret_cast<const short8*>(wpn + s * 512);
        }
        short8 bfr[4];
        #pragma unroll
        for (int s = 0; s < 4; ++s)
          bfr[s] = *reinterpret_cast<const short8*>(&smem[fr * SXW + n * 128 + s * 32 + fg * 8]);
        f32x4 acc = {0.f, 0.f, 0.f, 0.f};
        #pragma unroll
        for (int s = 0; s < 4; ++s)
          acc = __builtin_amdgcn_mfma_f32_16x16x32_bf16(wfr[j & 1][s], bfr[s], acc, 0, 0, 0);
        ushort4 d4;
        d4.x = f2bf(acc[0]); d4.y = f2bf(acc[1]);
        d4.z = f2bf(acc[2]); d4.w = f2bf(acc[3]);
        qreg[j] = d4;
      }
    }

    // ---- issue next tile's x loads: fly under qkv-write + B' + D ----
    if (it + 1 < NITER) {
      const float* xb = x + (tile0 + it + 1) * 16 * DIM;
      #pragma unroll
      for (int jj = 0; jj < 4; ++jj) {
        int chunk = tid + 512 * jj;
        const float* src = xb + (long)(chunk >> 7) * DIM + (chunk & 127) * 8;
        xa[jj] = *reinterpret_cast<const float4*>(src);
        xc[jj] = *reinterpret_cast<const float4*>(src + 4);
      }
    }
    __syncthreads();                         // x region dies

    // ---- write qkv frags; V transposed vT[dd][h*8+n] (R9) ----
    {
      #pragma unroll
      for (int j = 0; j < 12; ++j) {
        const int cc = w * 12 + j;
        const int met = cc >> 3, n = cc & 7;
        const int m = met >> 2, e0 = (met & 3) * 16;
        if (m < 2) {
          *reinterpret_cast<ushort4*>(&smem[fr * SQW + m * 512 + n * 64 + e0 + fg * 4]) = qreg[j];
        } else {
          const unsigned short vals[4] = {qreg[j].x, qreg[j].y, qreg[j].z, qreg[j].w};
          #pragma unroll
          for (int r = 0; r < 4; ++r) {
            int e = e0 + fg * 4 + r, dd = e & 31, h = e >> 5;
            smem[fr * SQW + 1024 + dd * 16 + h * 8 + n] = vals[r];
          }
        }
      }
    }
    __syncthreads();

    // ---- phase B': scores (MFMA) + softmax + PV (MFMA chain); R9 verbatim ----
    {
      const int la = lane & 15, ga = lane >> 4;
      const int rowoff = (la & 7) * 64 + (la >> 3) * 32;
      const bool useful = ((ga >> 1) == (la >> 3));
      const bool kvalid = (ga < 2);
      const int srcA = (ga * 32 + la) & 63;
      #pragma unroll
      for (int tt = 0; tt < 2; ++tt) {
        const int t = w * 2 + tt;
        const unsigned short* tb = &smem[t * SQW];
        short8 kfr = *reinterpret_cast<const short8*>(tb + 512 + rowoff + ga * 8);
        short8 qfr = *reinterpret_cast<const short8*>(tb + rowoff + ga * 8);
        f32x4 zero = {0.f, 0.f, 0.f, 0.f};
        f32x4 s = __builtin_amdgcn_mfma_f32_16x16x32_bf16(kfr, qfr, zero, 0, 0, 0);
        float m4 = fmaxf(fmaxf(s[0], s[1]), fmaxf(s[2], s[3]));
        float mx = fmaxf(m4, __shfl_xor(m4, 16));
        float e0 = __expf(s[0] - mx), e1 = __expf(s[1] - mx);
        float e2 = __expf(s[2] - mx), e3 = __expf(s[3] - mx);
        float sm  = e0 + e1 + e2 + e3;
        float smt = sm + __shfl_xor(sm, 16);
        float inv = useful ? (1.f / smt) : 0.f;
        unsigned pk01 = pack2bf(e0 * inv, e1 * inv);
        unsigned pk23 = pack2bf(e2 * inv, e3 * inv);
        unsigned b0 = (unsigned)__builtin_amdgcn_ds_bpermute(srcA * 4, (int)pk01);
        unsigned b1 = (unsigned)__builtin_amdgcn_ds_bpermute(srcA * 4, (int)pk23);
        unsigned b2 = (unsigned)__builtin_amdgcn_ds_bpermute(((srcA + 16) & 63) * 4, (int)pk01);
        unsigned b3 = (unsigned)__builtin_amdgcn_ds_bpermute(((srcA + 16) & 63) * 4, (int)pk23);
        union { unsigned u[4]; short8 s8; } pb;
        pb.u[0] = kvalid ? b0 : 0u;  pb.u[1] = kvalid ? b1 : 0u;
        pb.u[2] = kvalid ? b2 : 0u;  pb.u[3] = kvalid ? b3 : 0u;
        #pragma unroll
        for (int dh = 0; dh < 2; ++dh) {
          short8 va = *reinterpret_cast<const short8*>(
              tb + 1024 + (dh * 16 + la) * 16 + (ga & 1) * 8);
          f32x4 o = __builtin_amdgcn_mfma_f32_16x16x32_bf16(va, pb.s8, zero, 0, 0, 0);
          ushort4 ou;
          ou.x = f2bf(o[0]); ou.y = f2bf(o[1]); ou.z = f2bf(o[2]); ou.w = f2bf(o[3]);
          *reinterpret_cast<ushort4*>(
              &smem[t * SQW + (la & 7) * 64 + (la >> 3) * 32 + dh * 16 + ga * 4]) = ou;
        }
      }
    }
    __syncthreads();

    // ---- phase D: out = attn_out @ wf; wave w owns n = w (R9 verbatim) ----
    {
      const int n = w;
      short8 bfr[2];
      #pragma unroll
      for (int s = 0; s < 2; ++s)
        bfr[s] = *reinterpret_cast<const short8*>(&smem[fr * SQW + n * 64 + s * 32 + fg * 8]);
      #pragma unroll
      for (int et = 0; et < 8; ++et) {
        const unsigned short* wp = wsf + (n * 8 + et) * 1024 + lane * 8;
        f32x4 acc = {0.f, 0.f, 0.f, 0.f};
        #pragma unroll
        for (int s = 0; s < 2; ++s) {
          short8 af = *reinterpret_cast<const short8*>(wp + s * 512);
          acc = __builtin_amdgcn_mfma_f32_16x16x32_bf16(af, bfr[s], acc, 0, 0, 0);
        }
        float4 o; o.x = acc[0]; o.y = acc[1]; o.z = acc[2]; o.w = acc[3];
        *reinterpret_cast<float4*>(out + (tok0 + fr) * DIM + n * 128 + et * 16 + fg * 4) = o;
      }
    }
    if (it + 1 < NITER) __syncthreads();     // D reads done before next x overlay write
  }
}

extern "C" void kernel_launch(void* const* d_in, const int* in_sizes, int n_in,
                              void* d_out, int out_size, void* d_ws, size_t ws_size,
                              hipStream_t stream) {
  const float* x  = (const float*)d_in[0];
  const float* wq = (const float*)d_in[1];
  const float* wk = (const float*)d_in[2];
  const float* wv = (const float*)d_in[3];
  const float* wf = (const float*)d_in[4];
  float* out = (float*)d_out;
  unsigned short* ws = (unsigned short*)d_ws;

  prep_weights<<<dim3(1024), dim3(256), 0, stream>>>(wq, wk, wv, wf, ws);

  const int tokens = in_sizes[0] / DIM;   // 32768
  gc_fused<<<dim3(tokens / 16 / NITER), dim3(512), 0, stream>>>(
      x, ws, ws + 196608, out);
}

// Round 17
// 88.387 us; speedup vs baseline: 4.9578x; 4.9578x over previous
//
#include <hip/hip_runtime.h>
#include <math.h>

using short8  = __attribute__((ext_vector_type(8))) short;
using ushort8 = __attribute__((ext_vector_type(8))) unsigned short;
using f32x4   = __attribute__((ext_vector_type(4))) float;

constexpr int DIM = 1024, NB = 8, NH = 2, HD = 32;
constexpr float SCALE = 0.17677669529663687f;  // HD^-0.5, folded into wq at prep
constexpr int SXW = 1032;   // x-tile row stride (ushorts)
constexpr int SQW = 1544;   // qkv row stride (ushorts)

__device__ __forceinline__ unsigned short f2bf(float f) {
  unsigned u = __float_as_uint(f);
  u += 0x7fff + ((u >> 16) & 1);  // RNE
  return (unsigned short)(u >> 16);
}
__device__ __forceinline__ float bf2f(unsigned short h) {
  return __uint_as_float((unsigned)h << 16);
}
__device__ __forceinline__ unsigned pack2bf(float lo, float hi) {
  return (unsigned)f2bf(lo) | ((unsigned)f2bf(hi) << 16);
}

// ---- prep: weights -> bf16 in MFMA fragment order (verified round 5/7) ----
__global__ __launch_bounds__(256) void prep_weights(
    const float* __restrict__ wq, const float* __restrict__ wk,
    const float* __restrict__ wv, const float* __restrict__ wf,
    unsigned short* __restrict__ ws)
{
  int gid = blockIdx.x * 256 + threadIdx.x;   // 0..262143
  if (gid < 196608) {
    int t = gid >> 11, r = gid & 2047;
    int s = r >> 9, l = (r >> 3) & 63, z = r & 7;
    int met = t >> 3, n = t & 7, m = met >> 2, et = met & 3;
    int fr = l & 15, fg = l >> 4;
    int e = et * 16 + fr, k = s * 32 + fg * 8 + z;
    const float* w = (m == 0) ? wq : (m == 1) ? wk : wv;
    float v = w[n * 8192 + k * 64 + e];
    if (m == 0) v *= SCALE;
    ws[gid] = f2bf(v);
  } else {
    int g2 = gid - 196608;
    int t = g2 >> 10, r = g2 & 1023;
    int s = r >> 9, l = (r >> 3) & 63, z = r & 7;
    int n = t >> 3, et = t & 7;
    int fr = l & 15, fg = l >> 4;
    int eo = et * 16 + fr, k = s * 32 + fg * 8 + z;
    ws[gid] = f2bf(wf[n * 8192 + k * 128 + eo]);
  }
}

// ---- fused kernel: 16 tokens/WG, 512 threads, attention fully on MFMA ----
__global__ __launch_bounds__(512, 6) void gc_fused(
    const float* __restrict__ x,
    const unsigned short* __restrict__ wsw,   // 96 qkv tiles [2048]
    const unsigned short* __restrict__ wsf,   // 64 wf tiles  [1024]
    float* __restrict__ out)
{
  // overlays: stage-x rows at r*SXW; after barrier qkv rows at t*SQW.
  // per token row (1536 used of 1544): q/attn_out [0,512) as n*64+h*32+dd |
  // k [512,1024) as 512+n*64+h*32+dd | vT [1024,1536) as 1024+dd*16+(h*8+n).
  __shared__ __align__(16) unsigned short smem[16 * SQW];   // 49408 B -> 3 WG/CU

  const int tid  = threadIdx.x;
  const int lane = tid & 63;
  const int w    = tid >> 6;
  const int fr   = lane & 15;
  const int fg   = lane >> 4;
  const long tok0 = (long)blockIdx.x * 16;

  // ---- stage x -> bf16 LDS (coalesced; proven) ----
  {
    const float* xb = x + tok0 * DIM;
    float4 xa[4], xc[4];
    #pragma unroll
    for (int jj = 0; jj < 4; ++jj) {
      int chunk = tid + 512 * jj;                  // 32B chunks, 128 per token row
      const float* src = xb + (long)(chunk >> 7) * DIM + (chunk & 127) * 8;
      xa[jj] = *reinterpret_cast<const float4*>(src);
      xc[jj] = *reinterpret_cast<const float4*>(src + 4);
    }
    #pragma unroll
    for (int jj = 0; jj < 4; ++jj) {
      int chunk = tid + 512 * jj;
      ushort8 v;
      v[0] = f2bf(xa[jj].x); v[1] = f2bf(xa[jj].y);
      v[2] = f2bf(xa[jj].z); v[3] = f2bf(xa[jj].w);
      v[4] = f2bf(xc[jj].x); v[5] = f2bf(xc[jj].y);
      v[6] = f2bf(xc[jj].z); v[7] = f2bf(xc[jj].w);
      *reinterpret_cast<ushort8*>(&smem[(chunk >> 7) * SXW + (chunk & 127) * 8]) = v;
    }
  }
  __syncthreads();

  // ---- phase A: 96 QKV tiles over 8 waves, dbuf weight prefetch (proven) ----
  ushort4 qreg[12];
  {
    short8 wfr[2][4];
    const unsigned short* wp0 = wsw + (w * 12) * 2048 + lane * 8;
    #pragma unroll
    for (int s = 0; s < 4; ++s)
      wfr[0][s] = *reinterpret_cast<const short8*>(wp0 + s * 512);
    #pragma unroll
    for (int j = 0; j < 12; ++j) {
      const int cc = w * 12 + j;
      const int n  = cc & 7;
      if (j < 11) {
        const unsigned short* wpn = wsw + (cc + 1) * 2048 + lane * 8;
        #pragma unroll
        for (int s = 0; s < 4; ++s)
          wfr[(j + 1) & 1][s] = *reinterpret_cast<const short8*>(wpn + s * 512);
      }
      short8 bfr[4];
      #pragma unroll
      for (int s = 0; s < 4; ++s)
        bfr[s] = *reinterpret_cast<const short8*>(&smem[fr * SXW + n * 128 + s * 32 + fg * 8]);
      f32x4 acc = {0.f, 0.f, 0.f, 0.f};
      #pragma unroll
      for (int s = 0; s < 4; ++s)
        acc = __builtin_amdgcn_mfma_f32_16x16x32_bf16(wfr[j & 1][s], bfr[s], acc, 0, 0, 0);
      ushort4 d4;
      d4.x = f2bf(acc[0]); d4.y = f2bf(acc[1]);
      d4.z = f2bf(acc[2]); d4.w = f2bf(acc[3]);
      qreg[j] = d4;
    }
  }
  __syncthreads();                                 // x region dies

  // ---- write qkv frags; V goes in TRANSPOSED (vT[dd][h*8+n]) for PV b128 reads ----
  {
    #pragma unroll
    for (int j = 0; j < 12; ++j) {
      const int cc = w * 12 + j;
      const int met = cc >> 3, n = cc & 7;
      const int m = met >> 2, e0 = (met & 3) * 16;
      if (m < 2) {
        *reinterpret_cast<ushort4*>(&smem[fr * SQW + m * 512 + n * 64 + e0 + fg * 4]) = qreg[j];
      } else {
        const unsigned short vals[4] = {qreg[j].x, qreg[j].y, qreg[j].z, qreg[j].w};
        #pragma unroll
        for (int r = 0; r < 4; ++r) {
          int e = e0 + fg * 4 + r, dd = e & 31, h = e >> 5;
          smem[fr * SQW + 1024 + dd * 16 + h * 8 + n] = vals[r];
        }
      }
    }
  }
  __syncthreads();

  // ---- phase B': scores (MFMA) + softmax + PV (MFMA chain); proven ----
  {
    const int la = lane & 15, ga = lane >> 4;
    const int rowoff = (la & 7) * 64 + (la >> 3) * 32;
    const bool useful = ((ga >> 1) == (la >> 3));
    const bool kvalid = (ga < 2);
    const int srcA = (ga * 32 + la) & 63;
    #pragma unroll
    for (int tt = 0; tt < 2; ++tt) {
      const int t = w * 2 + tt;
      const unsigned short* tb = &smem[t * SQW];
      short8 kfr = *reinterpret_cast<const short8*>(tb + 512 + rowoff + ga * 8);
      short8 qfr = *reinterpret_cast<const short8*>(tb + rowoff + ga * 8);
      f32x4 zero = {0.f, 0.f, 0.f, 0.f};
      f32x4 s = __builtin_amdgcn_mfma_f32_16x16x32_bf16(kfr, qfr, zero, 0, 0, 0);
      float m4 = fmaxf(fmaxf(s[0], s[1]), fmaxf(s[2], s[3]));
      float mx = fmaxf(m4, __shfl_xor(m4, 16));
      float e0 = __expf(s[0] - mx), e1 = __expf(s[1] - mx);
      float e2 = __expf(s[2] - mx), e3 = __expf(s[3] - mx);
      float sm  = e0 + e1 + e2 + e3;
      float smt = sm + __shfl_xor(sm, 16);
      float inv = useful ? (1.f / smt) : 0.f;      // smt >= 1 for useful lanes
      unsigned pk01 = pack2bf(e0 * inv, e1 * inv);
      unsigned pk23 = pack2bf(e2 * inv, e3 * inv);
      unsigned b0 = (unsigned)__builtin_amdgcn_ds_bpermute(srcA * 4, (int)pk01);
      unsigned b1 = (unsigned)__builtin_amdgcn_ds_bpermute(srcA * 4, (int)pk23);
      unsigned b2 = (unsigned)__builtin_amdgcn_ds_bpermute(((srcA + 16) & 63) * 4, (int)pk01);
      unsigned b3 = (unsigned)__builtin_amdgcn_ds_bpermute(((srcA + 16) & 63) * 4, (int)pk23);
      union { unsigned u[4]; short8 s8; } pb;
      pb.u[0] = kvalid ? b0 : 0u;  pb.u[1] = kvalid ? b1 : 0u;
      pb.u[2] = kvalid ? b2 : 0u;  pb.u[3] = kvalid ? b3 : 0u;
      #pragma unroll
      for (int dh = 0; dh < 2; ++dh) {
        // A[row=la][k=ga*8+j] = vT[dd=dh*16+la][k]; ga>=2 reads (ga&1) copy:
        // valid finite data, multiplied by B rows 16..31 == 0.
        short8 va = *reinterpret_cast<const short8*>(
            tb + 1024 + (dh * 16 + la) * 16 + (ga & 1) * 8);
        f32x4 o = __builtin_amdgcn_mfma_f32_16x16x32_bf16(va, pb.s8, zero, 0, 0, 0);
        // D[i=ga*4+r][col=la] -> attn_out[n=la&7][h=la>>3][d=dh*16+ga*4+r]
        ushort4 ou;
        ou.x = f2bf(o[0]); ou.y = f2bf(o[1]); ou.z = f2bf(o[2]); ou.w = f2bf(o[3]);
        *reinterpret_cast<ushort4*>(
            &smem[t * SQW + (la & 7) * 64 + (la >> 3) * 32 + dh * 16 + ga * 4]) = ou;
      }
    }
  }
  __syncthreads();

  // ---- phase D: out = attn_out @ wf; wave w owns block n = w (proven) ----
  {
    const int n = w;
    short8 bfr[2];
    #pragma unroll
    for (int s = 0; s < 2; ++s)
      bfr[s] = *reinterpret_cast<const short8*>(&smem[fr * SQW + n * 64 + s * 32 + fg * 8]);
    #pragma unroll
    for (int et = 0; et < 8; ++et) {
      const unsigned short* wp = wsf + (n * 8 + et) * 1024 + lane * 8;
      f32x4 acc = {0.f, 0.f, 0.f, 0.f};
      #pragma unroll
      for (int s = 0; s < 2; ++s) {
        short8 af = *reinterpret_cast<const short8*>(wp + s * 512);
        acc = __builtin_amdgcn_mfma_f32_16x16x32_bf16(af, bfr[s], acc, 0, 0, 0);
      }
      float4 o; o.x = acc[0]; o.y = acc[1]; o.z = acc[2]; o.w = acc[3];
      *reinterpret_cast<float4*>(out + (tok0 + fr) * DIM + n * 128 + et * 16 + fg * 4) = o;
    }
  }
}

extern "C" void kernel_launch(void* const* d_in, const int* in_sizes, int n_in,
                              void* d_out, int out_size, void* d_ws, size_t ws_size,
                              hipStream_t stream) {
  const float* x  = (const float*)d_in[0];
  const float* wq = (const float*)d_in[1];
  const float* wk = (const float*)d_in[2];
  const float* wv = (const float*)d_in[3];
  const float* wf = (const float*)d_in[4];
  float* out = (float*)d_out;
  unsigned short* ws = (unsigned short*)d_ws;

  prep_weights<<<dim3(1024), dim3(256), 0, stream>>>(wq, wk, wv, wf, ws);

  const int tokens = in_sizes[0] / DIM;   // 32768
  gc_fused<<<dim3(tokens / 16), dim3(512), 0, stream>>>(x, ws, ws + 196608, out);
}